// Round 1
// baseline (1253.246 us; speedup 1.0000x reference)
//
#include <hip/hip_runtime.h>

typedef unsigned int u32;
typedef unsigned short u16;

#define NB 32
#define N0V 2048
#define FEATV 1036
#define NHIDV 128
#define EDGESV (NB*N0V*16)   // 1048576
#define KK1 410
#define KK2 82
#define KK3 17
#define NN1 (NB*N0V)   // 65536
#define NN2 (NB*KK1)   // 13120
#define NN3 (NB*KK2)   // 2624
#define NN4 (NB*KK3)   // 544
#define KP1 1056       // 33*32, zero-padded K for stage-1 GEMM
#define KP2 128

typedef __bf16 bf16x8 __attribute__((ext_vector_type(8)));
typedef float f32x4 __attribute__((ext_vector_type(4)));

__device__ inline u16 f2bf(float f){
  u32 u = __float_as_uint(f);
  u32 r = (u + 0x7FFFu + ((u >> 16) & 1u)) >> 16;   // RNE
  return (u16)r;
}
__device__ inline float bf2f(u16 h){ return __uint_as_float(((u32)h) << 16); }
__device__ inline float dec_ord(u32 u){
  u32 bits = (u & 0x80000000u) ? (u ^ 0x80000000u) : ~u;
  return __uint_as_float(bits);
}

// ---------------- utility fills ----------------
__global__ void fill_i32(int* p, int v, int n){
  int i = blockIdx.x*256 + threadIdx.x;
  if (i < n) p[i] = v;
}

// ---------------- column max of x[:, :12] (order-mapped uint atomicMax) -----
__global__ void colmax_kernel(const float* __restrict__ x, u32* mx){
  __shared__ float sm[256];
  float m[12];
  #pragma unroll
  for (int j=0;j<12;j++) m[j] = -3.4e38f;
  int t = threadIdx.x;
  for (int r = blockIdx.x*256 + t; r < NN1; r += gridDim.x*256){
    const float* row = x + (size_t)r*FEATV;
    #pragma unroll
    for (int j=0;j<12;j++) m[j] = fmaxf(m[j], row[j]);
  }
  for (int j=0;j<12;j++){
    sm[t] = m[j]; __syncthreads();
    for (int off=128; off>0; off>>=1){ if (t<off) sm[t]=fmaxf(sm[t],sm[t+off]); __syncthreads(); }
    if (t==0){
      u32 b = __float_as_uint(sm[0]);
      u32 u = (b & 0x80000000u) ? ~b : (b | 0x80000000u);
      atomicMax(&mx[j], u);
    }
    __syncthreads();
  }
}

// ------- build B^T (bf16 hi/lo) from Wl|Wr, optionally scaling rows k<12 ----
__global__ void wprep_kernel(const float* __restrict__ Wl, const float* __restrict__ Wr,
                             const u32* __restrict__ mxo, int K, int Kpad, int scale12,
                             u16* __restrict__ Bth, u16* __restrict__ Btl){
  int idx = blockIdx.x*256 + threadIdx.x;
  if (idx >= 256*Kpad) return;
  int n = idx / Kpad, k = idx - n*Kpad;
  float v = 0.f;
  if (k < K) v = (n < 128) ? Wl[(size_t)k*128 + n] : Wr[(size_t)k*128 + (n-128)];
  if (scale12 && k < 12) v /= dec_ord(mxo[k]);
  u16 h = f2bf(v);
  Bth[idx] = h;
  Btl[idx] = f2bf(v - bf2f(h));
}

// ---------------- split-bf16 GEMM: C[M,256] = A[M,K] * (Wl|Wr) -------------
// error-compensated: A=Ah+Al, B=Bh+Bl; C += Ah*Bh + Ah*Bl + Al*Bh (fp32-class)
__launch_bounds__(512)
__global__ void gemm_split_kernel(const float* __restrict__ A, int lda, int M,
                                  int Kvalid, int Kpad,
                                  const u16* __restrict__ Bth, const u16* __restrict__ Btl,
                                  float* __restrict__ C){
  __shared__ __align__(16) u16 Ah[128][40];
  __shared__ __align__(16) u16 Al[128][40];
  __shared__ __align__(16) u16 Bh[256][40];
  __shared__ __align__(16) u16 Bl[256][40];
  int tid = threadIdx.x;
  int row0 = blockIdx.x * 128;
  int w = tid >> 6, lane = tid & 63;
  int wm = w >> 2, wn = w & 3;          // wave grid 2(m) x 4(n); 64x64 per wave
  int lr = lane & 15, kh = lane >> 4;
  f32x4 acc[4][4];
  #pragma unroll
  for (int i=0;i<4;i++)
    #pragma unroll
    for (int j=0;j<4;j++) acc[i][j] = (f32x4){0.f,0.f,0.f,0.f};

  int Ksteps = Kpad >> 5;
  for (int kt = 0; kt < Ksteps; ++kt){
    int k0 = kt << 5;
    // stage A (fp32 -> hi/lo bf16), 128x32 tile
    #pragma unroll
    for (int s=0;s<2;s++){
      int i = tid + s*512;
      int r = i >> 3, c4 = (i & 7) << 2;
      int col = k0 + c4;
      float4 v = make_float4(0.f,0.f,0.f,0.f);
      if (row0 + r < M && col < Kvalid)
        v = *(const float4*)(A + (size_t)(row0 + r)*lda + col);
      ushort4 h, l;
      h.x=f2bf(v.x); l.x=f2bf(v.x-bf2f(h.x));
      h.y=f2bf(v.y); l.y=f2bf(v.y-bf2f(h.y));
      h.z=f2bf(v.z); l.z=f2bf(v.z-bf2f(h.z));
      h.w=f2bf(v.w); l.w=f2bf(v.w-bf2f(h.w));
      *(ushort4*)&Ah[r][c4] = h;
      *(ushort4*)&Al[r][c4] = l;
    }
    // stage B (already bf16 hi/lo in ws), 256x32 tile
    #pragma unroll
    for (int s=0;s<2;s++){
      int i = tid + s*512;
      int n = i >> 2, c8 = (i & 3) << 3;
      size_t go = (size_t)n*Kpad + k0 + c8;
      *(uint4*)&Bh[n][c8] = *(const uint4*)(Bth + go);
      *(uint4*)&Bl[n][c8] = *(const uint4*)(Btl + go);
    }
    __syncthreads();
    bf16x8 ah[4], al[4], bh[4], bl[4];
    #pragma unroll
    for (int mi=0;mi<4;mi++){
      int r = wm*64 + mi*16 + lr;
      ah[mi] = *(const bf16x8*)&Ah[r][kh*8];
      al[mi] = *(const bf16x8*)&Al[r][kh*8];
    }
    #pragma unroll
    for (int ni=0;ni<4;ni++){
      int n = wn*64 + ni*16 + lr;
      bh[ni] = *(const bf16x8*)&Bh[n][kh*8];
      bl[ni] = *(const bf16x8*)&Bl[n][kh*8];
    }
    #pragma unroll
    for (int mi=0;mi<4;mi++)
      #pragma unroll
      for (int ni=0;ni<4;ni++){
        acc[mi][ni] = __builtin_amdgcn_mfma_f32_16x16x32_bf16(ah[mi], bh[ni], acc[mi][ni], 0,0,0);
        acc[mi][ni] = __builtin_amdgcn_mfma_f32_16x16x32_bf16(ah[mi], bl[ni], acc[mi][ni], 0,0,0);
        acc[mi][ni] = __builtin_amdgcn_mfma_f32_16x16x32_bf16(al[mi], bh[ni], acc[mi][ni], 0,0,0);
      }
    __syncthreads();
  }
  // epilogue: C/D layout col=lane&15, row=(lane>>4)*4+reg  [verified mapping]
  #pragma unroll
  for (int mi=0;mi<4;mi++)
    #pragma unroll
    for (int j=0;j<4;j++){
      int row = row0 + wm*64 + mi*16 + kh*4 + j;
      if (row < M){
        #pragma unroll
        for (int ni=0;ni<4;ni++){
          int col = wn*64 + ni*16 + lr;
          C[(size_t)row*256 + col] = acc[mi][ni][j];
        }
      }
    }
}

// ---------------- CSR build ----------------
__global__ void hist_kernel(const int* __restrict__ dst, const int* ne_dev, int ne_max,
                            int* __restrict__ cnt){
  int i = blockIdx.x*256 + threadIdx.x;
  int ne = ne_dev ? *ne_dev : ne_max;
  if (i < ne) atomicAdd(&cnt[dst[i]], 1);
}

__global__ void scan_kernel(const int* __restrict__ deg, int* __restrict__ rowptr,
                            int* __restrict__ cur, int n){
  __shared__ int sd[1024];
  int t = threadIdx.x;
  int base = 0;
  for (int c0 = 0; c0 < n; c0 += 1024){
    int i = c0 + t;
    int v = (i < n) ? deg[i] : 0;
    sd[t] = v; __syncthreads();
    for (int off=1; off<1024; off<<=1){
      int xv = (t >= off) ? sd[t-off] : 0;
      __syncthreads();
      sd[t] += xv;
      __syncthreads();
    }
    if (i < n){ rowptr[i+1] = base + sd[t]; cur[i] = base + sd[t] - v; }
    int tot = sd[1023];
    __syncthreads();
    base += tot;
  }
  if (t == 0) rowptr[0] = 0;
}

__global__ void scatter_kernel(const int* __restrict__ src, const int* __restrict__ dst,
                               const int* ne_dev, int ne_max,
                               int* __restrict__ cur, int* __restrict__ adj){
  int i = blockIdx.x*256 + threadIdx.x;
  int ne = ne_dev ? *ne_dev : ne_max;
  if (i < ne){
    int p = atomicAdd(&cur[dst[i]], 1);
    adj[p] = src[i];
  }
}

// -------- SAGE finalize: x_out = relu(mean_in(hl) + bl + hr), wave per node --
__global__ void convfin_kernel(const float* __restrict__ hcomb, const int* __restrict__ rowptr,
                               const int* __restrict__ adj, const float* __restrict__ bl,
                               float* __restrict__ xout, int n){
  int w = (blockIdx.x*256 + threadIdx.x) >> 6;
  int lane = threadIdx.x & 63;
  if (w >= n) return;
  int s = rowptr[w], e = rowptr[w+1];
  float s0 = 0.f, s1 = 0.f;
  for (int t = s; t < e; ++t){
    const float* hj = hcomb + (size_t)adj[t]*256;
    s0 += hj[lane]; s1 += hj[lane+64];
  }
  float invc = 1.0f / fmaxf((float)(e - s), 1.0f);
  const float* hr = hcomb + (size_t)w*256 + 128;
  float o0 = s0*invc + bl[lane]    + hr[lane];
  float o1 = s1*invc + bl[lane+64] + hr[lane+64];
  xout[(size_t)w*128 + lane]      = fmaxf(o0, 0.f);
  xout[(size_t)w*128 + lane + 64] = fmaxf(o1, 0.f);
}

// -------- score GEMV h = x@Wp (wave per node) + degf = 1+indeg --------------
__global__ void scoregemv_kernel(const float* __restrict__ x, const float* __restrict__ Wp,
                                 const int* __restrict__ rowptr,
                                 float* __restrict__ hsc, float* __restrict__ degf, int n){
  int w = (blockIdx.x*256 + threadIdx.x) >> 6;
  int lane = threadIdx.x & 63;
  if (w >= n) return;
  const float* row = x + (size_t)w*128;
  float v = row[lane]*Wp[lane] + row[lane+64]*Wp[lane+64];
  #pragma unroll
  for (int off=32; off>0; off>>=1) v += __shfl_down(v, off);
  if (lane == 0){
    hsc[w] = v;
    degf[w] = (float)(1 + rowptr[w+1] - rowptr[w]);
  }
}

// -------- GCN score aggregation ---------------------------------------------
__global__ void scoreagg_kernel(const float* __restrict__ hsc, const float* __restrict__ degf,
                                const int* __restrict__ rowptr, const int* __restrict__ adj,
                                const float* __restrict__ bp, float* __restrict__ score, int n){
  int i = blockIdx.x*256 + threadIdx.x;
  if (i >= n) return;
  float di = degf[i];
  float rdi = 1.0f / sqrtf(di);
  float acc = hsc[i] / di;
  int s = rowptr[i], e = rowptr[i+1];
  for (int t = s; t < e; ++t){
    int j = adj[t];
    acc += hsc[j] * (1.0f / sqrtf(degf[j])) * rdi;
  }
  score[i] = acc + bp[0];
}

// -------- exact per-graph top-k (radix select on order-mapped bits) ---------
__global__ void topk_kernel(const float* __restrict__ score, int nper, int k,
                            int* __restrict__ perm, int* __restrict__ inv){
  __shared__ u32 su[2048];
  __shared__ int slist[448];
  __shared__ int scnt, ssel;
  int g = blockIdx.x, t = threadIdx.x;
  const float* sc = score + (size_t)g*nper;
  for (int i = t; i < nper; i += 256){
    u32 b = __float_as_uint(sc[i]);
    su[i] = (b & 0x80000000u) ? ~b : (b | 0x80000000u);
  }
  __syncthreads();
  u32 base = 0; int rem = k;
  for (int bit = 31; bit >= 0; --bit){
    if (t == 0) scnt = 0;
    __syncthreads();
    u32 maskAbove = (bit == 31) ? 0u : ~((1u << (bit+1)) - 1u);
    u32 bmask = 1u << bit;
    int c = 0;
    for (int i = t; i < nper; i += 256){
      u32 u = su[i];
      if ((u & maskAbove) == base && (u & bmask)) c++;
    }
    if (c) atomicAdd(&scnt, c);
    __syncthreads();
    int cnt = scnt;
    __syncthreads();
    if (cnt >= rem) base |= bmask; else rem -= cnt;
  }
  // base == value of k-th largest; select all > base, then ties by ascending index
  if (t == 0) ssel = 0;
  __syncthreads();
  for (int i = t; i < nper; i += 256)
    if (su[i] > base){ int p = atomicAdd(&ssel, 1); slist[p] = i; }
  __syncthreads();
  if (t == 0){
    int p = ssel;
    for (int i = 0; i < nper && p < k; ++i)
      if (su[i] == base) slist[p++] = i;
  }
  __syncthreads();
  for (int j = t; j < k; j += 256){
    int oldid = g*nper + slist[j];
    int newid = g*k + j;
    perm[newid] = oldid;
    inv[oldid] = newid;
  }
}

// -------- pooled gather: xp = x[perm] * tanh(score[perm]) -------------------
__global__ void poolgather_kernel(const float* __restrict__ x, const float* __restrict__ score,
                                  const int* __restrict__ perm, float* __restrict__ xp, int nk){
  int idx = blockIdx.x*256 + threadIdx.x;
  if (idx >= nk*128) return;
  int row = idx >> 7, c = idx & 127;
  int old = perm[row];
  xp[idx] = x[(size_t)old*128 + c] * tanhf(score[old]);
}

// -------- edge compaction through inv ---------------------------------------
__global__ void compact_kernel(const int* __restrict__ src, const int* __restrict__ dst,
                               const int* ne_dev, int ne_max, const int* __restrict__ inv,
                               int* __restrict__ osrc, int* __restrict__ odst, int* ocnt){
  int i = blockIdx.x*256 + threadIdx.x;
  int ne = ne_dev ? *ne_dev : ne_max;
  if (i >= ne) return;
  int s = inv[src[i]], d = inv[dst[i]];
  if (s >= 0 && d >= 0){
    int p = atomicAdd(ocnt, 1);
    osrc[p] = s; odst[p] = d;
  }
}

// -------- readout: [max | mean] over k nodes per graph ----------------------
__global__ void readout_kernel(const float* __restrict__ xp, int k, float* __restrict__ r){
  int g = blockIdx.x, c = threadIdx.x;   // 128 threads
  const float* p = xp + (size_t)g*k*128 + c;
  float mx = -3.4e38f, sm = 0.f;
  for (int j = 0; j < k; ++j){ float v = p[(size_t)j*128]; mx = fmaxf(mx, v); sm += v; }
  r[g*256 + c] = mx;
  r[g*256 + 128 + c] = sm / (float)k;
}

// -------- MLP head (single block) -------------------------------------------
__global__ void head_kernel(const float* __restrict__ r1, const float* __restrict__ r2,
                            const float* __restrict__ r3,
                            const float* __restrict__ w1, const float* __restrict__ b1,
                            const float* __restrict__ w2, const float* __restrict__ b2,
                            const float* __restrict__ w3, const float* __restrict__ b3,
                            float* __restrict__ out){
  __shared__ float hs[32][256];
  __shared__ float h1[32][128];
  __shared__ float ft[32][32];
  int t = threadIdx.x;
  for (int o = t; o < 32*256; o += 256) hs[o>>8][o&255] = r1[o]+r2[o]+r3[o];
  __syncthreads();
  for (int o = t; o < 32*128; o += 256){
    int i = o >> 7, j = o & 127;
    float a = b1[j];
    for (int c = 0; c < 256; ++c) a += hs[i][c]*w1[c*128 + j];
    h1[i][j] = fmaxf(a, 0.f);
  }
  __syncthreads();
  for (int o = t; o < 32*32; o += 256){
    int i = o >> 5, j = o & 31;
    float a = b2[j];
    for (int c = 0; c < 128; ++c) a += h1[i][c]*w2[c*32 + j];
    float v = fmaxf(a, 0.f);
    ft[i][j] = v;
    out[o] = v;                 // features [32,32]
  }
  __syncthreads();
  if (t < 32){
    float a = b3[0];
    for (int c = 0; c < 32; ++c) a += ft[t][c]*w3[c];
    out[1024 + t] = a;          // out [32,1]
  }
}

extern "C" void kernel_launch(void* const* d_in, const int* in_sizes, int n_in,
                              void* d_out, int out_size, void* d_ws, size_t ws_size,
                              hipStream_t stream){
  (void)in_sizes; (void)n_in; (void)out_size; (void)ws_size;
  const float* x   = (const float*)d_in[0];
  const int* esrc  = (const int*)d_in[1];
  const int* edst  = (const int*)d_in[2];
  const float* W1l = (const float*)d_in[3];
  const float* b1l = (const float*)d_in[4];
  const float* W1r = (const float*)d_in[5];
  const float* Wp1 = (const float*)d_in[6];
  const float* bp1 = (const float*)d_in[7];
  const float* W2l = (const float*)d_in[8];
  const float* b2l = (const float*)d_in[9];
  const float* W2r = (const float*)d_in[10];
  const float* Wp2 = (const float*)d_in[11];
  const float* bp2 = (const float*)d_in[12];
  const float* W3l = (const float*)d_in[13];
  const float* b3l = (const float*)d_in[14];
  const float* W3r = (const float*)d_in[15];
  const float* Wp3 = (const float*)d_in[16];
  const float* bp3 = (const float*)d_in[17];
  const float* l1w = (const float*)d_in[18];
  const float* l1b = (const float*)d_in[19];
  const float* l2w = (const float*)d_in[20];
  const float* l2b = (const float*)d_in[21];
  const float* l3w = (const float*)d_in[22];
  const float* l3b = (const float*)d_in[23];
  float* out = (float*)d_out;

  char* ws = (char*)d_ws;
  size_t off = 0;
  auto alloc = [&](size_t bytes)->char*{
    char* p = ws + off; off = (off + bytes + 255) & ~(size_t)255; return p;
  };

  // ---- zero group (one fill) ----
  size_t z0 = off;
  u32* mx      = (u32*)alloc(64);                 // mx[12] + counters
  int* ecnt1   = (int*)(mx + 12);
  int* ecnt2   = ecnt1 + 1;
  int* deg1cnt = (int*)alloc((size_t)NN1*4);
  int* deg2cnt = (int*)alloc((size_t)NN2*4);
  int* deg3cnt = (int*)alloc((size_t)NN3*4);
  size_t zend = off;
  // ---- -1 group (one fill) ----
  size_t m0 = off;
  int* inv1 = (int*)alloc((size_t)NN1*4);
  int* inv2 = (int*)alloc((size_t)NN2*4);
  int* inv3 = (int*)alloc((size_t)NN3*4);
  size_t mend = off;
  // ---- rest ----
  int* rowptr1 = (int*)alloc((size_t)(NN1+1)*4);
  int* cur1    = (int*)alloc((size_t)NN1*4);
  int* rowptr2 = (int*)alloc((size_t)(NN2+1)*4);
  int* cur2    = (int*)alloc((size_t)NN2*4);
  int* rowptr3 = (int*)alloc((size_t)(NN3+1)*4);
  int* cur3    = (int*)alloc((size_t)NN3*4);
  int* adj     = (int*)alloc((size_t)EDGESV*4);
  int* eAs     = (int*)alloc((size_t)EDGESV*4);
  int* eAd     = (int*)alloc((size_t)EDGESV*4);
  int* eBs     = (int*)alloc((size_t)EDGESV*4);
  int* eBd     = (int*)alloc((size_t)EDGESV*4);
  u16* Bt1h    = (u16*)alloc((size_t)256*KP1*2);
  u16* Bt1l    = (u16*)alloc((size_t)256*KP1*2);
  u16* Bt2h    = (u16*)alloc((size_t)256*KP2*2);
  u16* Bt2l    = (u16*)alloc((size_t)256*KP2*2);
  u16* Bt3h    = (u16*)alloc((size_t)256*KP2*2);
  u16* Bt3l    = (u16*)alloc((size_t)256*KP2*2);
  float* hcomb = (float*)alloc((size_t)NN1*256*4);
  float* x1    = (float*)alloc((size_t)NN1*128*4);
  float* x2    = (float*)alloc((size_t)NN2*128*4);
  float* x3    = (float*)alloc((size_t)NN3*128*4);
  float* xp1   = (float*)alloc((size_t)NN2*128*4);
  float* xp2   = (float*)alloc((size_t)NN3*128*4);
  float* xp3   = (float*)alloc((size_t)NN4*128*4);
  float* hsc   = (float*)alloc((size_t)NN1*4);
  float* degf  = (float*)alloc((size_t)NN1*4);
  float* score = (float*)alloc((size_t)NN1*4);
  int* perm1   = (int*)alloc((size_t)NN2*4);
  int* perm2   = (int*)alloc((size_t)NN3*4);
  int* perm3   = (int*)alloc((size_t)NN4*4);
  float* r1    = (float*)alloc((size_t)32*256*4);
  float* r2    = (float*)alloc((size_t)32*256*4);
  float* r3    = (float*)alloc((size_t)32*256*4);

  int zn = (int)((zend - z0) / 4);
  int mn = (int)((mend - m0) / 4);
  fill_i32<<<(zn+255)/256, 256, 0, stream>>>((int*)(ws + z0), 0, zn);
  fill_i32<<<(mn+255)/256, 256, 0, stream>>>((int*)(ws + m0), -1, mn);

  // ===== stage 1 =====
  colmax_kernel<<<64, 256, 0, stream>>>(x, mx);
  wprep_kernel<<<(256*KP1)/256, 256, 0, stream>>>(W1l, W1r, mx, FEATV, KP1, 1, Bt1h, Bt1l);
  gemm_split_kernel<<<NN1/128, 512, 0, stream>>>(x, FEATV, NN1, FEATV, KP1, Bt1h, Bt1l, hcomb);
  hist_kernel<<<EDGESV/256, 256, 0, stream>>>(edst, nullptr, EDGESV, deg1cnt);
  scan_kernel<<<1, 1024, 0, stream>>>(deg1cnt, rowptr1, cur1, NN1);
  scatter_kernel<<<EDGESV/256, 256, 0, stream>>>(esrc, edst, nullptr, EDGESV, cur1, adj);
  convfin_kernel<<<NN1/4, 256, 0, stream>>>(hcomb, rowptr1, adj, b1l, x1, NN1);
  scoregemv_kernel<<<NN1/4, 256, 0, stream>>>(x1, Wp1, rowptr1, hsc, degf, NN1);
  scoreagg_kernel<<<NN1/256, 256, 0, stream>>>(hsc, degf, rowptr1, adj, bp1, score, NN1);
  topk_kernel<<<NB, 256, 0, stream>>>(score, N0V, KK1, perm1, inv1);
  poolgather_kernel<<<(NN2*128)/256, 256, 0, stream>>>(x1, score, perm1, xp1, NN2);
  readout_kernel<<<NB, 128, 0, stream>>>(xp1, KK1, r1);
  compact_kernel<<<EDGESV/256, 256, 0, stream>>>(esrc, edst, nullptr, EDGESV, inv1, eAs, eAd, ecnt1);

  // ===== stage 2 =====
  wprep_kernel<<<(256*KP2)/256, 256, 0, stream>>>(W2l, W2r, mx, NHIDV, KP2, 0, Bt2h, Bt2l);
  gemm_split_kernel<<<(NN2+127)/128, 512, 0, stream>>>(xp1, 128, NN2, 128, KP2, Bt2h, Bt2l, hcomb);
  hist_kernel<<<EDGESV/256, 256, 0, stream>>>(eAd, ecnt1, EDGESV, deg2cnt);
  scan_kernel<<<1, 1024, 0, stream>>>(deg2cnt, rowptr2, cur2, NN2);
  scatter_kernel<<<EDGESV/256, 256, 0, stream>>>(eAs, eAd, ecnt1, EDGESV, cur2, adj);
  convfin_kernel<<<NN2/4, 256, 0, stream>>>(hcomb, rowptr2, adj, b2l, x2, NN2);
  scoregemv_kernel<<<NN2/4, 256, 0, stream>>>(x2, Wp2, rowptr2, hsc, degf, NN2);
  scoreagg_kernel<<<(NN2+255)/256, 256, 0, stream>>>(hsc, degf, rowptr2, adj, bp2, score, NN2);
  topk_kernel<<<NB, 256, 0, stream>>>(score, KK1, KK2, perm2, inv2);
  poolgather_kernel<<<(NN3*128)/256, 256, 0, stream>>>(x2, score, perm2, xp2, NN3);
  readout_kernel<<<NB, 128, 0, stream>>>(xp2, KK2, r2);
  compact_kernel<<<EDGESV/256, 256, 0, stream>>>(eAs, eAd, ecnt1, EDGESV, inv2, eBs, eBd, ecnt2);

  // ===== stage 3 =====
  wprep_kernel<<<(256*KP2)/256, 256, 0, stream>>>(W3l, W3r, mx, NHIDV, KP2, 0, Bt3h, Bt3l);
  gemm_split_kernel<<<(NN3+127)/128, 512, 0, stream>>>(xp2, 128, NN3, 128, KP2, Bt3h, Bt3l, hcomb);
  hist_kernel<<<EDGESV/256, 256, 0, stream>>>(eBd, ecnt2, EDGESV, deg3cnt);
  scan_kernel<<<1, 1024, 0, stream>>>(deg3cnt, rowptr3, cur3, NN3);
  scatter_kernel<<<EDGESV/256, 256, 0, stream>>>(eBs, eBd, ecnt2, EDGESV, cur3, adj);
  convfin_kernel<<<NN3/4, 256, 0, stream>>>(hcomb, rowptr3, adj, b3l, x3, NN3);
  scoregemv_kernel<<<NN3/4, 256, 0, stream>>>(x3, Wp3, rowptr3, hsc, degf, NN3);
  scoreagg_kernel<<<(NN3+255)/256, 256, 0, stream>>>(hsc, degf, rowptr3, adj, bp3, score, NN3);
  topk_kernel<<<NB, 256, 0, stream>>>(score, KK2, KK3, perm3, inv3);
  poolgather_kernel<<<(NN4*128)/256, 256, 0, stream>>>(x3, score, perm3, xp3, NN4);
  readout_kernel<<<NB, 128, 0, stream>>>(xp3, KK3, r3);

  // ===== head =====
  head_kernel<<<1, 256, 0, stream>>>(r1, r2, r3, l1w, l1b, l2w, l2b, l3w, l3b, out);
}

// Round 2
// 941.497 us; speedup vs baseline: 1.3311x; 1.3311x over previous
//
#include <hip/hip_runtime.h>

typedef unsigned int u32;
typedef unsigned short u16;

#define NB 32
#define N0V 2048
#define FEATV 1036
#define NHIDV 128
#define EDGESV (NB*N0V*16)   // 1048576
#define KK1 410
#define KK2 82
#define KK3 17
#define NN1 (NB*N0V)   // 65536
#define NN2 (NB*KK1)   // 13120
#define NN3 (NB*KK2)   // 2624
#define NN4 (NB*KK3)   // 544
#define KSTEP1 33      // ceil(1036/32)
#define KSTEP2 4       // 128/32

typedef __bf16 bf16x8 __attribute__((ext_vector_type(8)));
typedef float f32x4 __attribute__((ext_vector_type(4)));

__device__ inline u16 f2bf(float f){
  u32 u = __float_as_uint(f);
  u32 r = (u + 0x7FFFu + ((u >> 16) & 1u)) >> 16;   // RNE
  return (u16)r;
}
__device__ inline float bf2f(u16 h){ return __uint_as_float(((u32)h) << 16); }
__device__ inline float dec_ord(u32 u){
  u32 bits = (u & 0x80000000u) ? (u ^ 0x80000000u) : ~u;
  return __uint_as_float(bits);
}
__device__ inline void gload_lds16(const void* g, void* l){
  __builtin_amdgcn_global_load_lds(
      (const __attribute__((address_space(1))) unsigned int*)g,
      (__attribute__((address_space(3))) unsigned int*)l, 16, 0, 0);
}

// ---------------- utility fills ----------------
__global__ void fill_i32(int* p, int v, int n){
  int i = blockIdx.x*256 + threadIdx.x;
  if (i < n) p[i] = v;
}

// ---------------- column max of x[:, :12] -----------------------------------
__global__ void colmax_kernel(const float* __restrict__ x, u32* mx){
  __shared__ float sm[256];
  float m[12];
  #pragma unroll
  for (int j=0;j<12;j++) m[j] = -3.4e38f;
  int t = threadIdx.x;
  for (int r = blockIdx.x*256 + t; r < NN1; r += gridDim.x*256){
    const float* row = x + (size_t)r*FEATV;
    #pragma unroll
    for (int j=0;j<12;j++) m[j] = fmaxf(m[j], row[j]);
  }
  for (int j=0;j<12;j++){
    sm[t] = m[j]; __syncthreads();
    for (int off=128; off>0; off>>=1){ if (t<off) sm[t]=fmaxf(sm[t],sm[t+off]); __syncthreads(); }
    if (t==0){
      u32 b = __float_as_uint(sm[0]);
      u32 u = (b & 0x80000000u) ? ~b : (b | 0x80000000u);
      atomicMax(&mx[j], u);
    }
    __syncthreads();
  }
}

// ------- build tiled B^T (bf16 hi/lo): layout [kt][256 n][32 kk] ------------
__global__ void wprep_kernel(const float* __restrict__ Wl, const float* __restrict__ Wr,
                             const u32* __restrict__ mxo, int K, int Ksteps, int scale12,
                             u16* __restrict__ Bth, u16* __restrict__ Btl){
  int idx = blockIdx.x*256 + threadIdx.x;
  if (idx >= Ksteps*8192) return;
  int kt = idx >> 13;
  int rem = idx & 8191;
  int n = rem >> 5;
  int kk = rem & 31;
  int k = (kt << 5) + kk;
  float v = 0.f;
  if (k < K) v = (n < 128) ? Wl[(size_t)k*128 + n] : Wr[(size_t)k*128 + (n-128)];
  if (scale12 && k < 12) v /= dec_ord(mxo[k]);
  u16 h = f2bf(v);
  Bth[idx] = h;
  Btl[idx] = f2bf(v - bf2f(h));
}

// ---------------- split-bf16 GEMM: C[M,256] = A[M,K] * (Wl|Wr) --------------
// 64x256 tile, 4 waves (each 64 rows x 64 cols), B via global_load_lds.
__launch_bounds__(256)
__global__ void gemm_split_kernel(const float* __restrict__ A, int lda, int M,
                                  int Kvalid, int Ksteps,
                                  const u16* __restrict__ Bth, const u16* __restrict__ Btl,
                                  float* __restrict__ C){
  __shared__ __align__(16) u16 Ah[64*32];
  __shared__ __align__(16) u16 Al[64*32];
  __shared__ __align__(16) u16 Bh[256*32];
  __shared__ __align__(16) u16 Bl[256*32];
  int tid = threadIdx.x;
  int row0 = blockIdx.x * 64;
  int w = tid >> 6, lane = tid & 63;
  int lr = lane & 15, kh = lane >> 4;
  f32x4 acc[4][4];
  #pragma unroll
  for (int i=0;i<4;i++)
    #pragma unroll
    for (int j=0;j<4;j++) acc[i][j] = (f32x4){0.f,0.f,0.f,0.f};

  for (int kt = 0; kt < Ksteps; ++kt){
    int k0 = kt << 5;
    // B tile (16 KB each) direct global->LDS, linear [256][32] u16
    #pragma unroll
    for (int j=0;j<4;j++){
      int slot = w*4 + j;
      const u16* sh = Bth + ((size_t)kt << 13) + slot*512 + lane*8;
      const u16* sl = Btl + ((size_t)kt << 13) + slot*512 + lane*8;
      gload_lds16(sh, &Bh[slot*512]);
      gload_lds16(sl, &Bl[slot*512]);
    }
    // A tile 64x32 fp32 -> hi/lo bf16
    #pragma unroll
    for (int s2=0;s2<2;s2++){
      int f = tid + s2*256;
      int r = f >> 3, c4 = (f & 7) << 2;
      int col = k0 + c4;
      float4 v = make_float4(0.f,0.f,0.f,0.f);
      if (row0 + r < M && col < Kvalid)
        v = *(const float4*)(A + (size_t)(row0 + r)*lda + col);
      ushort4 h, l;
      h.x=f2bf(v.x); l.x=f2bf(v.x-bf2f(h.x));
      h.y=f2bf(v.y); l.y=f2bf(v.y-bf2f(h.y));
      h.z=f2bf(v.z); l.z=f2bf(v.z-bf2f(h.z));
      h.w=f2bf(v.w); l.w=f2bf(v.w-bf2f(h.w));
      *(ushort4*)&Ah[r*32 + c4] = h;
      *(ushort4*)&Al[r*32 + c4] = l;
    }
    __syncthreads();
    bf16x8 ah[4], al[4], bh[4], bl[4];
    #pragma unroll
    for (int mi=0;mi<4;mi++){
      int r = mi*16 + lr;
      ah[mi] = *(const bf16x8*)&Ah[r*32 + kh*8];
      al[mi] = *(const bf16x8*)&Al[r*32 + kh*8];
    }
    #pragma unroll
    for (int ni=0;ni<4;ni++){
      int n = w*64 + ni*16 + lr;
      bh[ni] = *(const bf16x8*)&Bh[n*32 + kh*8];
      bl[ni] = *(const bf16x8*)&Bl[n*32 + kh*8];
    }
    #pragma unroll
    for (int mi=0;mi<4;mi++)
      #pragma unroll
      for (int ni=0;ni<4;ni++){
        acc[mi][ni] = __builtin_amdgcn_mfma_f32_16x16x32_bf16(ah[mi], bh[ni], acc[mi][ni], 0,0,0);
        acc[mi][ni] = __builtin_amdgcn_mfma_f32_16x16x32_bf16(ah[mi], bl[ni], acc[mi][ni], 0,0,0);
        acc[mi][ni] = __builtin_amdgcn_mfma_f32_16x16x32_bf16(al[mi], bh[ni], acc[mi][ni], 0,0,0);
      }
    __syncthreads();
  }
  #pragma unroll
  for (int mi=0;mi<4;mi++)
    #pragma unroll
    for (int j=0;j<4;j++){
      int row = row0 + mi*16 + kh*4 + j;
      if (row < M){
        #pragma unroll
        for (int ni=0;ni<4;ni++){
          int col = w*64 + ni*16 + lr;
          C[(size_t)row*256 + col] = acc[mi][ni][j];
        }
      }
    }
}

// ---------------- CSR build ----------------
__global__ void hist_kernel(const int* __restrict__ dst, int ne, int* __restrict__ cnt){
  int i = blockIdx.x*256 + threadIdx.x;
  if (i < ne) atomicAdd(&cnt[dst[i]], 1);
}

__global__ void scan_part(const int* __restrict__ deg, int* __restrict__ tmp,
                          int* __restrict__ partial, int n){
  __shared__ int sd[1024];
  int t = threadIdx.x, i = blockIdx.x*1024 + t;
  int v = (i < n) ? deg[i] : 0;
  sd[t] = v; __syncthreads();
  for (int off=1; off<1024; off<<=1){
    int xv = (t >= off) ? sd[t-off] : 0;
    __syncthreads();
    sd[t] += xv;
    __syncthreads();
  }
  if (i < n) tmp[i] = sd[t];
  if (t == 1023) partial[blockIdx.x] = sd[1023];
}

__global__ void scan_fix(const int* __restrict__ tmp, const int* __restrict__ deg,
                         const int* __restrict__ partial,
                         int* __restrict__ rowptr, int* __restrict__ cur, int n){
  __shared__ int sp[64];
  __shared__ int sbase;
  int t = threadIdx.x, b = blockIdx.x;
  if (t < 64) sp[t] = (t < b) ? partial[t] : 0;
  __syncthreads();
  if (t == 0){ int s = 0; for (int j=0;j<64;j++) s += sp[j]; sbase = s; }
  __syncthreads();
  int i = b*1024 + t;
  if (i < n){
    int inc = tmp[i] + sbase;
    rowptr[i+1] = inc;
    cur[i] = inc - deg[i];
  }
  if (b == 0 && t == 0) rowptr[0] = 0;
}

__global__ void scatter_kernel(const int* __restrict__ src, const int* __restrict__ dst,
                               const int* ne_dev, int ne_max,
                               int* __restrict__ cur, int* __restrict__ adj){
  int i = blockIdx.x*256 + threadIdx.x;
  int ne = ne_dev ? *ne_dev : ne_max;
  if (i < ne){
    int p = atomicAdd(&cur[dst[i]], 1);
    adj[p] = src[i];
  }
}

// -------- SAGE finalize + fused score GEMV (wave per node) ------------------
__global__ void convfin_kernel(const float* __restrict__ hcomb, const int* __restrict__ rowptr,
                               const int* __restrict__ adj, const float* __restrict__ bl,
                               const float* __restrict__ Wp,
                               float* __restrict__ xout, float* __restrict__ hsc,
                               float* __restrict__ degf, int n){
  int w = (blockIdx.x*256 + threadIdx.x) >> 6;
  int lane = threadIdx.x & 63;
  if (w >= n) return;
  int s = rowptr[w], e = rowptr[w+1];
  float s0 = 0.f, s1 = 0.f;
  for (int t = s; t < e; ++t){
    float2 hj = *(const float2*)(hcomb + (size_t)adj[t]*256 + 2*lane);
    s0 += hj.x; s1 += hj.y;
  }
  float invc = 1.0f / fmaxf((float)(e - s), 1.0f);
  float2 hr = *(const float2*)(hcomb + (size_t)w*256 + 128 + 2*lane);
  float2 bb = *(const float2*)(bl + 2*lane);
  float o0 = fmaxf(s0*invc + bb.x + hr.x, 0.f);
  float o1 = fmaxf(s1*invc + bb.y + hr.y, 0.f);
  *(float2*)(xout + (size_t)w*128 + 2*lane) = make_float2(o0, o1);
  float2 wp = *(const float2*)(Wp + 2*lane);
  float v = o0*wp.x + o1*wp.y;
  #pragma unroll
  for (int off=32; off>0; off>>=1) v += __shfl_down(v, off);
  if (lane == 0){
    hsc[w] = v;
    degf[w] = (float)(1 + e - s);
  }
}

// -------- GCN score aggregation ---------------------------------------------
__global__ void scoreagg_kernel(const float* __restrict__ hsc, const float* __restrict__ degf,
                                const int* __restrict__ rowptr, const int* __restrict__ adj,
                                const float* __restrict__ bp, float* __restrict__ score, int n){
  int i = blockIdx.x*256 + threadIdx.x;
  if (i >= n) return;
  float di = degf[i];
  float rdi = 1.0f / sqrtf(di);
  float acc = hsc[i] / di;
  int s = rowptr[i], e = rowptr[i+1];
  for (int t = s; t < e; ++t){
    int j = adj[t];
    acc += hsc[j] * (1.0f / sqrtf(degf[j])) * rdi;
  }
  score[i] = acc + bp[0];
}

// -------- per-graph top-k: 4-pass radix-256 histogram select ----------------
__global__ void topk_kernel(const float* __restrict__ score, int nper, int k,
                            int* __restrict__ perm, int* __restrict__ inv,
                            float* __restrict__ pscale){
  __shared__ u32 su[2048];
  __shared__ int bins[256];
  __shared__ int slist[416];
  __shared__ int tlist[64];
  __shared__ u32 spfx;
  __shared__ int srem, ssel, stie;
  int g = blockIdx.x, t = threadIdx.x;
  const float* sc = score + (size_t)g*nper;
  for (int i = t; i < nper; i += 256){
    u32 b = __float_as_uint(sc[i]);
    su[i] = (b & 0x80000000u) ? ~b : (b | 0x80000000u);
  }
  if (t == 0){ spfx = 0; srem = k; }
  __syncthreads();
  for (int pass = 0; pass < 4; ++pass){
    int shift = 24 - 8*pass;
    bins[t] = 0;
    __syncthreads();
    u32 pfx = spfx;
    for (int i = t; i < nper; i += 256){
      u32 u = su[i];
      bool match = (pass == 0) || ((u >> (shift+8)) == (pfx >> (shift+8)));
      if (match) atomicAdd(&bins[(u >> shift) & 255], 1);
    }
    __syncthreads();
    if (t == 0){
      int rem = srem, c = 0, b = 255;
      for (; b >= 0; --b){ c += bins[b]; if (c >= rem) break; }
      srem = rem - (c - bins[b]);
      spfx = spfx | ((u32)b << shift);
    }
    __syncthreads();
  }
  u32 th = spfx;
  if (t == 0){ ssel = 0; stie = 0; }
  __syncthreads();
  for (int i = t; i < nper; i += 256)
    if (su[i] > th){ int p = atomicAdd(&ssel, 1); slist[p] = i; }
  __syncthreads();
  for (int i = t; i < nper; i += 256)
    if (su[i] == th){ int q = atomicAdd(&stie, 1); if (q < 64) tlist[q] = i; }
  __syncthreads();
  if (t == 0){
    int p = ssel, need = k - p;
    if (need > 0){
      if (stie <= 64){
        for (int a = 1; a < stie; ++a){
          int v = tlist[a], b2 = a-1;
          while (b2 >= 0 && tlist[b2] > v){ tlist[b2+1] = tlist[b2]; b2--; }
          tlist[b2+1] = v;
        }
        for (int m = 0; m < need; ++m) slist[p+m] = tlist[m];
      } else {
        for (int i = 0; i < nper && p < k; ++i)
          if (su[i] == th) slist[p++] = i;
      }
    }
  }
  __syncthreads();
  for (int j = t; j < k; j += 256){
    int oldid = g*nper + slist[j];
    int newid = g*k + j;
    perm[newid] = oldid;
    inv[oldid] = newid;
    pscale[newid] = tanhf(sc[slist[j]]);
  }
}

// -------- pooled gather (vectorized, pre-hoisted tanh) ----------------------
__global__ void poolgather_kernel(const float* __restrict__ x, const int* __restrict__ perm,
                                  const float* __restrict__ pscale,
                                  float* __restrict__ xp, int nk){
  int idx = blockIdx.x*256 + threadIdx.x;
  if (idx >= nk*32) return;
  int row = idx >> 5, c4 = (idx & 31) << 2;
  int old = perm[row];
  float s = pscale[row];
  float4 v = *(const float4*)(x + (size_t)old*128 + c4);
  v.x *= s; v.y *= s; v.z *= s; v.w *= s;
  *(float4*)(xp + (size_t)idx*4) = v;
}

// -------- edge compaction + fused next-stage histogram ----------------------
__global__ void compact_kernel(const int* __restrict__ src, const int* __restrict__ dst,
                               const int* ne_dev, int ne_max, const int* __restrict__ inv,
                               int* __restrict__ osrc, int* __restrict__ odst,
                               int* ocnt, int* __restrict__ ndeg){
  int i = blockIdx.x*256 + threadIdx.x;
  int ne = ne_dev ? *ne_dev : ne_max;
  if (i >= ne) return;
  int s = inv[src[i]], d = inv[dst[i]];
  if (s >= 0 && d >= 0){
    int p = atomicAdd(ocnt, 1);
    osrc[p] = s; odst[p] = d;
    atomicAdd(&ndeg[d], 1);
  }
}

// -------- readout: [max | mean] over k nodes per graph (2-way k split) ------
__global__ void readout_kernel(const float* __restrict__ xp, int k, float* __restrict__ r){
  __shared__ float smx[256], ssm[256];
  int g = blockIdx.x, t = threadIdx.x;
  int half = t >> 7, c = t & 127;
  int j0 = half ? (k >> 1) : 0;
  int j1 = half ? k : (k >> 1);
  const float* p = xp + (size_t)g*k*128 + c;
  float mx = -3.4e38f, sm = 0.f;
  for (int j = j0; j < j1; ++j){ float v = p[(size_t)j*128]; mx = fmaxf(mx, v); sm += v; }
  smx[t] = mx; ssm[t] = sm;
  __syncthreads();
  if (t < 128){
    r[g*256 + t] = fmaxf(smx[t], smx[t+128]);
    r[g*256 + 128 + t] = (ssm[t] + ssm[t+128]) / (float)k;
  }
}

// -------- MLP head (single block) -------------------------------------------
__global__ void head_kernel(const float* __restrict__ r1, const float* __restrict__ r2,
                            const float* __restrict__ r3,
                            const float* __restrict__ w1, const float* __restrict__ b1,
                            const float* __restrict__ w2, const float* __restrict__ b2,
                            const float* __restrict__ w3, const float* __restrict__ b3,
                            float* __restrict__ out){
  __shared__ float hs[32][256];
  __shared__ float h1[32][128];
  __shared__ float ft[32][32];
  int t = threadIdx.x;
  for (int o = t; o < 32*256; o += 256) hs[o>>8][o&255] = r1[o]+r2[o]+r3[o];
  __syncthreads();
  for (int o = t; o < 32*128; o += 256){
    int i = o >> 7, j = o & 127;
    float a = b1[j];
    for (int c = 0; c < 256; ++c) a += hs[i][c]*w1[c*128 + j];
    h1[i][j] = fmaxf(a, 0.f);
  }
  __syncthreads();
  for (int o = t; o < 32*32; o += 256){
    int i = o >> 5, j = o & 31;
    float a = b2[j];
    for (int c = 0; c < 128; ++c) a += h1[i][c]*w2[c*32 + j];
    float v = fmaxf(a, 0.f);
    ft[i][j] = v;
    out[o] = v;
  }
  __syncthreads();
  if (t < 32){
    float a = b3[0];
    for (int c = 0; c < 32; ++c) a += ft[t][c]*w3[c];
    out[1024 + t] = a;
  }
}

extern "C" void kernel_launch(void* const* d_in, const int* in_sizes, int n_in,
                              void* d_out, int out_size, void* d_ws, size_t ws_size,
                              hipStream_t stream){
  (void)in_sizes; (void)n_in; (void)out_size; (void)ws_size;
  const float* x   = (const float*)d_in[0];
  const int* esrc  = (const int*)d_in[1];
  const int* edst  = (const int*)d_in[2];
  const float* W1l = (const float*)d_in[3];
  const float* b1l = (const float*)d_in[4];
  const float* W1r = (const float*)d_in[5];
  const float* Wp1 = (const float*)d_in[6];
  const float* bp1 = (const float*)d_in[7];
  const float* W2l = (const float*)d_in[8];
  const float* b2l = (const float*)d_in[9];
  const float* W2r = (const float*)d_in[10];
  const float* Wp2 = (const float*)d_in[11];
  const float* bp2 = (const float*)d_in[12];
  const float* W3l = (const float*)d_in[13];
  const float* b3l = (const float*)d_in[14];
  const float* W3r = (const float*)d_in[15];
  const float* Wp3 = (const float*)d_in[16];
  const float* bp3 = (const float*)d_in[17];
  const float* l1w = (const float*)d_in[18];
  const float* l1b = (const float*)d_in[19];
  const float* l2w = (const float*)d_in[20];
  const float* l2b = (const float*)d_in[21];
  const float* l3w = (const float*)d_in[22];
  const float* l3b = (const float*)d_in[23];
  float* out = (float*)d_out;

  char* ws = (char*)d_ws;
  size_t off = 0;
  auto alloc = [&](size_t bytes)->char*{
    char* p = ws + off; off = (off + bytes + 255) & ~(size_t)255; return p;
  };

  // ---- zero group ----
  size_t z0 = off;
  u32* mx      = (u32*)alloc(64);
  int* ecnt1   = (int*)(mx + 12);
  int* ecnt2   = ecnt1 + 1;
  int* deg1cnt = (int*)alloc((size_t)NN1*4);
  int* deg2cnt = (int*)alloc((size_t)NN2*4);
  int* deg3cnt = (int*)alloc((size_t)NN3*4);
  size_t zend = off;
  // ---- -1 group ----
  size_t m0 = off;
  int* inv1 = (int*)alloc((size_t)NN1*4);
  int* inv2 = (int*)alloc((size_t)NN2*4);
  int* inv3 = (int*)alloc((size_t)NN3*4);
  size_t mend = off;
  // ---- rest ----
  int* rowptr1 = (int*)alloc((size_t)(NN1+1)*4);
  int* cur1    = (int*)alloc((size_t)NN1*4);
  int* rowptr2 = (int*)alloc((size_t)(NN2+1)*4);
  int* cur2    = (int*)alloc((size_t)NN2*4);
  int* rowptr3 = (int*)alloc((size_t)(NN3+1)*4);
  int* cur3    = (int*)alloc((size_t)NN3*4);
  int* scan_tmp= (int*)alloc((size_t)NN1*4);
  int* partial = (int*)alloc((size_t)128*4);
  int* adj     = (int*)alloc((size_t)EDGESV*4);
  int* eAs     = (int*)alloc((size_t)EDGESV*4);
  int* eAd     = (int*)alloc((size_t)EDGESV*4);
  int* eBs     = (int*)alloc((size_t)EDGESV*4);
  int* eBd     = (int*)alloc((size_t)EDGESV*4);
  u16* Bt1h    = (u16*)alloc((size_t)KSTEP1*8192*2);
  u16* Bt1l    = (u16*)alloc((size_t)KSTEP1*8192*2);
  u16* Bt2h    = (u16*)alloc((size_t)KSTEP2*8192*2);
  u16* Bt2l    = (u16*)alloc((size_t)KSTEP2*8192*2);
  u16* Bt3h    = (u16*)alloc((size_t)KSTEP2*8192*2);
  u16* Bt3l    = (u16*)alloc((size_t)KSTEP2*8192*2);
  float* hcomb = (float*)alloc((size_t)NN1*256*4);
  float* x1    = (float*)alloc((size_t)NN1*128*4);
  float* x2    = (float*)alloc((size_t)NN2*128*4);
  float* x3    = (float*)alloc((size_t)NN3*128*4);
  float* xp1   = (float*)alloc((size_t)NN2*128*4);
  float* xp2   = (float*)alloc((size_t)NN3*128*4);
  float* xp3   = (float*)alloc((size_t)NN4*128*4);
  float* hsc   = (float*)alloc((size_t)NN1*4);
  float* degf  = (float*)alloc((size_t)NN1*4);
  float* score = (float*)alloc((size_t)NN1*4);
  float* pscale= (float*)alloc((size_t)NN2*4);
  int* perm1   = (int*)alloc((size_t)NN2*4);
  int* perm2   = (int*)alloc((size_t)NN3*4);
  int* perm3   = (int*)alloc((size_t)NN4*4);
  float* r1    = (float*)alloc((size_t)32*256*4);
  float* r2    = (float*)alloc((size_t)32*256*4);
  float* r3    = (float*)alloc((size_t)32*256*4);

  int zn = (int)((zend - z0) / 4);
  int mn = (int)((mend - m0) / 4);
  fill_i32<<<(zn+255)/256, 256, 0, stream>>>((int*)(ws + z0), 0, zn);
  fill_i32<<<(mn+255)/256, 256, 0, stream>>>((int*)(ws + m0), -1, mn);

  // ===== stage 1 =====
  colmax_kernel<<<64, 256, 0, stream>>>(x, mx);
  wprep_kernel<<<(KSTEP1*8192+255)/256, 256, 0, stream>>>(W1l, W1r, mx, FEATV, KSTEP1, 1, Bt1h, Bt1l);
  gemm_split_kernel<<<NN1/64, 256, 0, stream>>>(x, FEATV, NN1, FEATV, KSTEP1, Bt1h, Bt1l, hcomb);
  hist_kernel<<<EDGESV/256, 256, 0, stream>>>(edst, EDGESV, deg1cnt);
  scan_part<<<NN1/1024, 1024, 0, stream>>>(deg1cnt, scan_tmp, partial, NN1);
  scan_fix<<<NN1/1024, 1024, 0, stream>>>(scan_tmp, deg1cnt, partial, rowptr1, cur1, NN1);
  scatter_kernel<<<EDGESV/256, 256, 0, stream>>>(esrc, edst, nullptr, EDGESV, cur1, adj);
  convfin_kernel<<<NN1/4, 256, 0, stream>>>(hcomb, rowptr1, adj, b1l, Wp1, x1, hsc, degf, NN1);
  scoreagg_kernel<<<NN1/256, 256, 0, stream>>>(hsc, degf, rowptr1, adj, bp1, score, NN1);
  topk_kernel<<<NB, 256, 0, stream>>>(score, N0V, KK1, perm1, inv1, pscale);
  poolgather_kernel<<<(NN2*32+255)/256, 256, 0, stream>>>(x1, perm1, pscale, xp1, NN2);
  readout_kernel<<<NB, 256, 0, stream>>>(xp1, KK1, r1);
  compact_kernel<<<EDGESV/256, 256, 0, stream>>>(esrc, edst, nullptr, EDGESV, inv1, eAs, eAd, ecnt1, deg2cnt);

  // ===== stage 2 =====
  wprep_kernel<<<(KSTEP2*8192+255)/256, 256, 0, stream>>>(W2l, W2r, mx, NHIDV, KSTEP2, 0, Bt2h, Bt2l);
  gemm_split_kernel<<<(NN2+63)/64, 256, 0, stream>>>(xp1, 128, NN2, 128, KSTEP2, Bt2h, Bt2l, hcomb);
  scan_part<<<(NN2+1023)/1024, 1024, 0, stream>>>(deg2cnt, scan_tmp, partial, NN2);
  scan_fix<<<(NN2+1023)/1024, 1024, 0, stream>>>(scan_tmp, deg2cnt, partial, rowptr2, cur2, NN2);
  scatter_kernel<<<EDGESV/256, 256, 0, stream>>>(eAs, eAd, ecnt1, EDGESV, cur2, adj);
  convfin_kernel<<<NN2/4, 256, 0, stream>>>(hcomb, rowptr2, adj, b2l, Wp2, x2, hsc, degf, NN2);
  scoreagg_kernel<<<(NN2+255)/256, 256, 0, stream>>>(hsc, degf, rowptr2, adj, bp2, score, NN2);
  topk_kernel<<<NB, 256, 0, stream>>>(score, KK1, KK2, perm2, inv2, pscale);
  poolgather_kernel<<<(NN3*32+255)/256, 256, 0, stream>>>(x2, perm2, pscale, xp2, NN3);
  readout_kernel<<<NB, 256, 0, stream>>>(xp2, KK2, r2);
  compact_kernel<<<EDGESV/256, 256, 0, stream>>>(eAs, eAd, ecnt1, EDGESV, inv2, eBs, eBd, ecnt2, deg3cnt);

  // ===== stage 3 =====
  wprep_kernel<<<(KSTEP2*8192+255)/256, 256, 0, stream>>>(W3l, W3r, mx, NHIDV, KSTEP2, 0, Bt3h, Bt3l);
  gemm_split_kernel<<<(NN3+63)/64, 256, 0, stream>>>(xp2, 128, NN3, 128, KSTEP2, Bt3h, Bt3l, hcomb);
  scan_part<<<(NN3+1023)/1024, 1024, 0, stream>>>(deg3cnt, scan_tmp, partial, NN3);
  scan_fix<<<(NN3+1023)/1024, 1024, 0, stream>>>(scan_tmp, deg3cnt, partial, rowptr3, cur3, NN3);
  scatter_kernel<<<EDGESV/256, 256, 0, stream>>>(eBs, eBd, ecnt2, EDGESV, cur3, adj);
  convfin_kernel<<<NN3/4, 256, 0, stream>>>(hcomb, rowptr3, adj, b3l, Wp3, x3, hsc, degf, NN3);
  scoreagg_kernel<<<(NN3+255)/256, 256, 0, stream>>>(hsc, degf, rowptr3, adj, bp3, score, NN3);
  topk_kernel<<<NB, 256, 0, stream>>>(score, KK2, KK3, perm3, inv3, pscale);
  poolgather_kernel<<<(NN4*32+255)/256, 256, 0, stream>>>(x3, perm3, pscale, xp3, NN4);
  readout_kernel<<<NB, 256, 0, stream>>>(xp3, KK3, r3);

  // ===== head =====
  head_kernel<<<1, 256, 0, stream>>>(r1, r2, r3, l1w, l1b, l2w, l2b, l3w, l3b, out);
}

// Round 3
// 741.266 us; speedup vs baseline: 1.6907x; 1.2701x over previous
//
#include <hip/hip_runtime.h>

typedef unsigned int u32;
typedef unsigned short u16;

#define NB 32
#define N0V 2048
#define FEATV 1036
#define EDGESV (NB*N0V*16)   // 1048576
#define KK1 410
#define KK2 82
#define KK3 17
#define NN1 (NB*N0V)   // 65536
#define NN2 (NB*KK1)   // 13120
#define NN3 (NB*KK2)   // 2624
#define NN4 (NB*KK3)   // 544
#define KSTEP1 33      // ceil(1036/32)
#define KSTEP2 4       // 128/32
#define ESTR 32768     // per-graph edge region stride

typedef __bf16 bf16x8 __attribute__((ext_vector_type(8)));
typedef float f32x4 __attribute__((ext_vector_type(4)));

__device__ inline u16 f2bf(float f){
  u32 u = __float_as_uint(f);
  u32 r = (u + 0x7FFFu + ((u >> 16) & 1u)) >> 16;   // RNE
  return (u16)r;
}
__device__ inline float bf2f(u16 h){ return __uint_as_float(((u32)h) << 16); }
__device__ inline float dec_ord(u32 u){
  u32 bits = (u & 0x80000000u) ? (u ^ 0x80000000u) : ~u;
  return __uint_as_float(bits);
}
__device__ inline void gload_lds16(const void* g, void* l){
  __builtin_amdgcn_global_load_lds(
      (const __attribute__((address_space(1))) unsigned int*)g,
      (__attribute__((address_space(3))) unsigned int*)l, 16, 0, 0);
}
__device__ inline void cvt4(float4 v, ushort4& h, ushort4& l){
  h.x=f2bf(v.x); l.x=f2bf(v.x-bf2f(h.x));
  h.y=f2bf(v.y); l.y=f2bf(v.y-bf2f(h.y));
  h.z=f2bf(v.z); l.z=f2bf(v.z-bf2f(h.z));
  h.w=f2bf(v.w); l.w=f2bf(v.w-bf2f(h.w));
}

// ---------------- init fills (one kernel) ------------------------------------
__global__ void init_kernel(int* pz, int nz, int* pm, int nm){
  int i = blockIdx.x*256 + threadIdx.x;
  if (i < nz) pz[i] = 0;
  if (i < nm) pm[i] = -1;
}

// ---------------- column max of x[:, :12] ------------------------------------
__global__ void colmax_kernel(const float* __restrict__ x, u32* mx){
  __shared__ float sm[256];
  float m[12];
  #pragma unroll
  for (int j=0;j<12;j++) m[j] = -3.4e38f;
  int t = threadIdx.x;
  for (int r = blockIdx.x*256 + t; r < NN1; r += gridDim.x*256){
    const float* row = x + (size_t)r*FEATV;
    #pragma unroll
    for (int j=0;j<12;j++) m[j] = fmaxf(m[j], row[j]);
  }
  for (int j=0;j<12;j++){
    sm[t] = m[j]; __syncthreads();
    for (int off=128; off>0; off>>=1){ if (t<off) sm[t]=fmaxf(sm[t],sm[t+off]); __syncthreads(); }
    if (t==0){
      u32 b = __float_as_uint(sm[0]);
      u32 u = (b & 0x80000000u) ? ~b : (b | 0x80000000u);
      atomicMax(&mx[j], u);
    }
    __syncthreads();
  }
}

// ------- build tiled B^T images for all 3 stages ------------------------------
// image element offset = kt*8192 + khg*2048 + n*8 + kk8  <->  W(k = kt*32+khg*8+kk8, n)
__global__ void wprep_all(const float* __restrict__ W1l, const float* __restrict__ W1r,
                          const float* __restrict__ W2l, const float* __restrict__ W2r,
                          const float* __restrict__ W3l, const float* __restrict__ W3r,
                          const u32* __restrict__ mxo,
                          u16* __restrict__ B1h, u16* __restrict__ B1l,
                          u16* __restrict__ B2h, u16* __restrict__ B2l,
                          u16* __restrict__ B3h, u16* __restrict__ B3l){
  int idx = blockIdx.x*256 + threadIdx.x;
  const float *Wl, *Wr; u16 *oh, *ol; int K, o, scale12;
  if (idx < KSTEP1*8192){ Wl=W1l; Wr=W1r; oh=B1h; ol=B1l; K=FEATV; o=idx; scale12=1; }
  else if (idx < (KSTEP1+KSTEP2)*8192){ Wl=W2l; Wr=W2r; oh=B2h; ol=B2l; K=128; o=idx-KSTEP1*8192; scale12=0; }
  else if (idx < (KSTEP1+2*KSTEP2)*8192){ Wl=W3l; Wr=W3r; oh=B3h; ol=B3l; K=128; o=idx-(KSTEP1+KSTEP2)*8192; scale12=0; }
  else return;
  int kt = o >> 13, r13 = o & 8191;
  int khg = r13 >> 11, n = (r13 >> 3) & 255, kk8 = r13 & 7;
  int k = (kt << 5) + khg*8 + kk8;
  float v = 0.f;
  if (k < K) v = (n < 128) ? Wl[(size_t)k*128 + n] : Wr[(size_t)k*128 + (n-128)];
  if (scale12 && k < 12) v /= dec_ord(mxo[k]);
  u16 h = f2bf(v);
  oh[o] = h;
  ol[o] = f2bf(v - bf2f(h));
}

// ---------------- pipelined split-bf16 GEMM: C[M,256] = A[M,K]*(Wl|Wr) --------
// 64x256 tile, 4 waves, double-buffered LDS, counted vmcnt, raw barriers.
// Requires M % 64 == 0, Ksteps >= 3.
__launch_bounds__(256, 2)
__global__ void gemm_split_kernel(const float* __restrict__ A, int lda, int M,
                                  int Kvalid, int Ksteps,
                                  const u16* __restrict__ Bth, const u16* __restrict__ Btl,
                                  float* __restrict__ C){
  // LDS slabs: A [2 buf][4 khg][64 row][8 u16]; B [2 buf][4 khg][256 n][8 u16]
  __shared__ __align__(16) u16 Ah[2][2048];
  __shared__ __align__(16) u16 Al[2][2048];
  __shared__ __align__(16) u16 Bh[2][8192];
  __shared__ __align__(16) u16 Bl[2][8192];
  int tid = threadIdx.x;
  int row0 = blockIdx.x * 64;
  int w = tid >> 6, lane = tid & 63;
  int lr = lane & 15, kh = lane >> 4;

  // A staging geometry: piece p (0..511) -> khg=p>>7, row=(p&127)>>1, half=p&1
  int p0i = tid, p1i = tid + 256;
  int kg0 = p0i >> 7, rw0 = (p0i & 127) >> 1, hf0 = p0i & 1;
  int kg1 = p1i >> 7, rw1 = (p1i & 127) >> 1, hf1 = p1i & 1;
  int coff0 = kg0*8 + hf0*4, coff1 = kg1*8 + hf1*4;
  const float* pA0 = A + (size_t)(row0 + rw0)*lda + coff0;
  const float* pA1 = A + (size_t)(row0 + rw1)*lda + coff1;
  int wi0 = kg0*512 + rw0*8 + hf0*4;
  int wi1 = kg1*512 + rw1*8 + hf1*4;

  f32x4 acc[4][4];
  #pragma unroll
  for (int i=0;i<4;i++)
    #pragma unroll
    for (int j=0;j<4;j++) acc[i][j] = (f32x4){0.f,0.f,0.f,0.f};

  float4 z4 = make_float4(0.f,0.f,0.f,0.f);

#define LOADA(KT, V0, V1) { int k0_ = (KT)<<5; \
    V0 = (k0_ + coff0 < Kvalid) ? *(const float4*)(pA0 + k0_) : z4; \
    V1 = (k0_ + coff1 < Kvalid) ? *(const float4*)(pA1 + k0_) : z4; }

#define ISSUEB(KT, BUF) { size_t tb_ = (size_t)(KT)*8192; \
    _Pragma("unroll") \
    for (int j_=0;j_<4;j_++){ int o_ = j_*2048 + w*512; \
      gload_lds16(Bth + tb_ + o_ + lane*8, &Bh[BUF][o_]); \
      gload_lds16(Btl + tb_ + o_ + lane*8, &Bl[BUF][o_]); } }

#define CVTWRITE(V0, V1, BUF) { ushort4 h_, l_; \
    cvt4(V0, h_, l_); *(ushort4*)&Ah[BUF][wi0] = h_; *(ushort4*)&Al[BUF][wi0] = l_; \
    cvt4(V1, h_, l_); *(ushort4*)&Ah[BUF][wi1] = h_; *(ushort4*)&Al[BUF][wi1] = l_; }

  // ---- prologue ----
  float4 a0, a1, pp0, pp1;
  LOADA(0, a0, a1);            // +2 vmem
  ISSUEB(0, 0);                // +8 vmem
  LOADA(1, pp0, pp1);          // +2 vmem
  CVTWRITE(a0, a1, 0);         // compiler waits a0/a1 (vmcnt<=10)
  asm volatile("s_waitcnt lgkmcnt(0)" ::: "memory");
  asm volatile("s_waitcnt vmcnt(2)" ::: "memory");   // B(0) landed (A(1) may fly)
  __builtin_amdgcn_s_barrier();

  for (int kt = 0; kt < Ksteps; ++kt){
    int cur = kt & 1, nxt = cur ^ 1;
    if (kt+1 < Ksteps) ISSUEB(kt+1, nxt);
    float4 n0 = z4, n1 = z4;
    if (kt+2 < Ksteps) LOADA(kt+2, n0, n1);
    // B(kt) landed: counted wait (per-wave; each wave consumes only its own B slots)
    if (kt+2 < Ksteps)      asm volatile("s_waitcnt vmcnt(12)" ::: "memory");
    else if (kt+1 < Ksteps) asm volatile("s_waitcnt vmcnt(10)" ::: "memory");
    else                    asm volatile("s_waitcnt vmcnt(0)"  ::: "memory");

    bf16x8 fah[4], fal[4], fbh[4], fbl[4];
    #pragma unroll
    for (int mi=0;mi<4;mi++){
      int idx = kh*512 + (mi*16 + lr)*8;
      fah[mi] = *(const bf16x8*)&Ah[cur][idx];
      fal[mi] = *(const bf16x8*)&Al[cur][idx];
    }
    #pragma unroll
    for (int ni=0;ni<4;ni++){
      int idx = kh*2048 + (w*64 + ni*16 + lr)*8;
      fbh[ni] = *(const bf16x8*)&Bh[cur][idx];
      fbl[ni] = *(const bf16x8*)&Bl[cur][idx];
    }
    if (kt+1 < Ksteps) CVTWRITE(pp0, pp1, nxt);   // waits A(kt+1) regs (vmcnt<=10)
    asm volatile("s_waitcnt lgkmcnt(0)" ::: "memory");
    __builtin_amdgcn_sched_barrier(0);            // keep MFMA below the wait
    __builtin_amdgcn_s_setprio(1);
    #pragma unroll
    for (int mi=0;mi<4;mi++)
      #pragma unroll
      for (int ni=0;ni<4;ni++){
        acc[mi][ni] = __builtin_amdgcn_mfma_f32_16x16x32_bf16(fah[mi], fbh[ni], acc[mi][ni], 0,0,0);
        acc[mi][ni] = __builtin_amdgcn_mfma_f32_16x16x32_bf16(fah[mi], fbl[ni], acc[mi][ni], 0,0,0);
        acc[mi][ni] = __builtin_amdgcn_mfma_f32_16x16x32_bf16(fal[mi], fbh[ni], acc[mi][ni], 0,0,0);
      }
    __builtin_amdgcn_s_setprio(0);
    pp0 = n0; pp1 = n1;
    __builtin_amdgcn_s_barrier();
  }
#undef LOADA
#undef ISSUEB
#undef CVTWRITE
  // epilogue: C/D layout col=lane&15, row=(lane>>4)*4+reg
  #pragma unroll
  for (int mi=0;mi<4;mi++)
    #pragma unroll
    for (int j=0;j<4;j++){
      int row = row0 + mi*16 + kh*4 + j;
      #pragma unroll
      for (int ni=0;ni<4;ni++){
        int col = w*64 + ni*16 + lr;
        C[(size_t)row*256 + col] = acc[mi][ni][j];
      }
    }
}

// ---------------- per-graph CSR build (hist+scan+scatter in one block) --------
__launch_bounds__(1024)
__global__ void csr_kernel(const int* __restrict__ src, const int* __restrict__ dst,
                           const int* ecnt_in, int isLocal, int nper,
                           int* __restrict__ rps, int* __restrict__ rpd,
                           int* __restrict__ adj){
  __shared__ int cnt[2048];
  __shared__ int part[1024];
  int g = blockIdx.x, t = threadIdx.x;
  for (int i = t; i < nper; i += 1024) cnt[i] = 0;
  __syncthreads();
  int ne = ecnt_in ? ecnt_in[g] : ESTR;
  size_t eb = (size_t)g*ESTR;
  for (int e = t; e < ne; e += 1024){
    int d = dst[eb+e];
    int dl = isLocal ? d : d - g*nper;
    atomicAdd(&cnt[dl], 1);
  }
  __syncthreads();
  int chunk = (nper + 1023) >> 10;
  int c0 = t*chunk, ssum = 0;
  for (int u=0; u<chunk; u++){ int i=c0+u; if (i<nper) ssum += cnt[i]; }
  part[t] = ssum; __syncthreads();
  for (int off=1; off<1024; off<<=1){
    int v = (t >= off) ? part[t-off] : 0;
    __syncthreads();
    part[t] += v;
    __syncthreads();
  }
  int run = part[t] - ssum;  // exclusive base for this chunk
  for (int u=0; u<chunk; u++){
    int i = c0+u;
    if (i < nper){
      int c = cnt[i];
      rps[g*nper + i] = g*ESTR + run;
      rpd[g*nper + i] = c;
      cnt[i] = run;          // becomes cur[]
      run += c;
    }
  }
  __syncthreads();
  for (int e = t; e < ne; e += 1024){
    int d = dst[eb+e], s = src[eb+e];
    int dl = isLocal ? d : d - g*nper;
    int p = atomicAdd(&cnt[dl], 1);
    adj[eb + p] = isLocal ? (g*nper + s) : s;   // store GLOBAL source id
  }
}

// -------- SAGE finalize + fused score GEMV (wave per node) -------------------
__global__ void convfin_kernel(const float* __restrict__ hcomb, const int* __restrict__ rps,
                               const int* __restrict__ rpd, const int* __restrict__ adj,
                               const float* __restrict__ bl, const float* __restrict__ Wp,
                               float* __restrict__ xout, float* __restrict__ hsc, int n){
  int w = (blockIdx.x*256 + threadIdx.x) >> 6;
  int lane = threadIdx.x & 63;
  if (w >= n) return;
  int s = rps[w], d = rpd[w];
  float s0 = 0.f, s1 = 0.f;
  for (int t = s; t < s+d; ++t){
    float2 hj = *(const float2*)(hcomb + (size_t)adj[t]*256 + 2*lane);
    s0 += hj.x; s1 += hj.y;
  }
  float invc = 1.0f / fmaxf((float)d, 1.0f);
  float2 hr = *(const float2*)(hcomb + (size_t)w*256 + 128 + 2*lane);
  float2 bb = *(const float2*)(bl + 2*lane);
  float o0 = fmaxf(s0*invc + bb.x + hr.x, 0.f);
  float o1 = fmaxf(s1*invc + bb.y + hr.y, 0.f);
  *(float2*)(xout + (size_t)w*128 + 2*lane) = make_float2(o0, o1);
  float2 wp = *(const float2*)(Wp + 2*lane);
  float v = o0*wp.x + o1*wp.y;
  #pragma unroll
  for (int off=32; off>0; off>>=1) v += __shfl_down(v, off);
  if (lane == 0) hsc[w] = v;
}

// -------- fused GCN score + per-graph top-k (radix-256 select) ---------------
__global__ void topk_kernel(const float* __restrict__ hsc, const int* __restrict__ rps,
                            const int* __restrict__ rpd, const int* __restrict__ adj,
                            const float* __restrict__ bp, int nper, int k,
                            int* __restrict__ perm, int* __restrict__ inv,
                            float* __restrict__ pscale){
  __shared__ u32 su[2048];
  __shared__ int bins[256];
  __shared__ int slist[416];
  __shared__ int tlist[64];
  __shared__ u32 spfx;
  __shared__ int srem, ssel, stie;
  int g = blockIdx.x, t = threadIdx.x;
  int gbase = g*nper;
  float bpv = bp[0];
  for (int i = t; i < nper; i += 256){
    int gi = gbase + i;
    float di = 1.0f + (float)rpd[gi];
    float rdi = 1.0f / sqrtf(di);
    float acc = hsc[gi] / di;
    int s = rps[gi], d = rpd[gi];
    for (int e = s; e < s+d; ++e){
      int j = adj[e];
      acc += hsc[j] * (1.0f / sqrtf(1.0f + (float)rpd[j])) * rdi;
    }
    float sc = acc + bpv;
    u32 b = __float_as_uint(sc);
    su[i] = (b & 0x80000000u) ? ~b : (b | 0x80000000u);
  }
  if (t == 0){ spfx = 0; srem = k; }
  __syncthreads();
  for (int pass = 0; pass < 4; ++pass){
    int shift = 24 - 8*pass;
    bins[t] = 0;
    __syncthreads();
    u32 pfx = spfx;
    for (int i = t; i < nper; i += 256){
      u32 u = su[i];
      bool match = (pass == 0) || ((u >> (shift+8)) == (pfx >> (shift+8)));
      if (match) atomicAdd(&bins[(u >> shift) & 255], 1);
    }
    __syncthreads();
    if (t == 0){
      int rem = srem, c = 0, b = 255;
      for (; b >= 0; --b){ c += bins[b]; if (c >= rem) break; }
      srem = rem - (c - bins[b]);
      spfx = spfx | ((u32)b << shift);
    }
    __syncthreads();
  }
  u32 th = spfx;
  if (t == 0){ ssel = 0; stie = 0; }
  __syncthreads();
  for (int i = t; i < nper; i += 256)
    if (su[i] > th){ int p = atomicAdd(&ssel, 1); slist[p] = i; }
  __syncthreads();
  for (int i = t; i < nper; i += 256)
    if (su[i] == th){ int q = atomicAdd(&stie, 1); if (q < 64) tlist[q] = i; }
  __syncthreads();
  if (t == 0){
    int p = ssel, need = k - p;
    if (need > 0){
      if (stie <= 64){
        for (int a = 1; a < stie; ++a){
          int v = tlist[a], b2 = a-1;
          while (b2 >= 0 && tlist[b2] > v){ tlist[b2+1] = tlist[b2]; b2--; }
          tlist[b2+1] = v;
        }
        for (int m = 0; m < need; ++m) slist[p+m] = tlist[m];
      } else {
        for (int i = 0; i < nper && p < k; ++i)
          if (su[i] == th) slist[p++] = i;
      }
    }
  }
  __syncthreads();
  for (int j = t; j < k; j += 256){
    int oldid = gbase + slist[j];
    int newid = g*k + j;
    perm[newid] = oldid;
    inv[oldid] = newid;
    pscale[newid] = tanhf(dec_ord(su[slist[j]]));
  }
}

// -------- fused pool-gather + readout + edge compaction ----------------------
__launch_bounds__(512)
__global__ void poolro_kernel(const float* __restrict__ x, const int* __restrict__ perm,
                              const float* __restrict__ pscale, int k,
                              float* __restrict__ xp, float* __restrict__ r,
                              const int* __restrict__ src, const int* __restrict__ dst,
                              const int* ecnt_in, int isLocal, int nperIn,
                              const int* __restrict__ inv, int kout,
                              int* __restrict__ osrc, int* __restrict__ odst,
                              int* __restrict__ ecnt_out){
  __shared__ float smx[512], ssm[512];
  __shared__ int lcnt;
  int g = blockIdx.x, t = threadIdx.x;
  int c = t & 127, q = t >> 7;
  float mx = -3.4e38f, sm = 0.f;
  for (int j = q; j < k; j += 4){
    int old = perm[g*k + j];
    float v = x[(size_t)old*128 + c] * pscale[g*k + j];
    xp[(size_t)(g*k + j)*128 + c] = v;
    mx = fmaxf(mx, v); sm += v;
  }
  smx[t] = mx; ssm[t] = sm;
  if (t == 0) lcnt = 0;
  __syncthreads();
  if (t < 128){
    float m2 = fmaxf(fmaxf(smx[t], smx[t+128]), fmaxf(smx[t+256], smx[t+384]));
    float s2 = ssm[t] + ssm[t+128] + ssm[t+256] + ssm[t+384];
    r[g*256 + t] = m2;
    r[g*256 + 128 + t] = s2 / (float)k;
  }
  if (osrc){
    int ne = ecnt_in ? ecnt_in[g] : ESTR;
    size_t eb = (size_t)g*ESTR;
    for (int e = t; e < ne; e += 512){
      int s = src[eb+e], d = dst[eb+e];
      int sg = isLocal ? (g*nperIn + s) : s;
      int dg = isLocal ? (g*nperIn + d) : d;
      int ns = inv[sg], nd = inv[dg];
      if (ns >= 0 && nd >= 0){
        int p = atomicAdd(&lcnt, 1);
        osrc[eb + p] = ns - g*kout;
        odst[eb + p] = nd - g*kout;
      }
    }
    __syncthreads();
    if (t == 0) ecnt_out[g] = lcnt;
  }
}

// -------- MLP head (single block) --------------------------------------------
__global__ void head_kernel(const float* __restrict__ r1, const float* __restrict__ r2,
                            const float* __restrict__ r3,
                            const float* __restrict__ w1, const float* __restrict__ b1,
                            const float* __restrict__ w2, const float* __restrict__ b2,
                            const float* __restrict__ w3, const float* __restrict__ b3,
                            float* __restrict__ out){
  __shared__ float hs[32][256];
  __shared__ float h1[32][128];
  __shared__ float ft[32][32];
  int t = threadIdx.x;
  for (int o = t; o < 32*256; o += 256) hs[o>>8][o&255] = r1[o]+r2[o]+r3[o];
  __syncthreads();
  for (int o = t; o < 32*128; o += 256){
    int i = o >> 7, j = o & 127;
    float a = b1[j];
    for (int c = 0; c < 256; ++c) a += hs[i][c]*w1[c*128 + j];
    h1[i][j] = fmaxf(a, 0.f);
  }
  __syncthreads();
  for (int o = t; o < 32*32; o += 256){
    int i = o >> 5, j = o & 31;
    float a = b2[j];
    for (int c = 0; c < 128; ++c) a += h1[i][c]*w2[c*32 + j];
    float v = fmaxf(a, 0.f);
    ft[i][j] = v;
    out[o] = v;
  }
  __syncthreads();
  if (t < 32){
    float a = b3[0];
    for (int c = 0; c < 32; ++c) a += ft[t][c]*w3[c];
    out[1024 + t] = a;
  }
}

extern "C" void kernel_launch(void* const* d_in, const int* in_sizes, int n_in,
                              void* d_out, int out_size, void* d_ws, size_t ws_size,
                              hipStream_t stream){
  (void)in_sizes; (void)n_in; (void)out_size; (void)ws_size;
  const float* x   = (const float*)d_in[0];
  const int* esrc  = (const int*)d_in[1];
  const int* edst  = (const int*)d_in[2];
  const float* W1l = (const float*)d_in[3];
  const float* b1l = (const float*)d_in[4];
  const float* W1r = (const float*)d_in[5];
  const float* Wp1 = (const float*)d_in[6];
  const float* bp1 = (const float*)d_in[7];
  const float* W2l = (const float*)d_in[8];
  const float* b2l = (const float*)d_in[9];
  const float* W2r = (const float*)d_in[10];
  const float* Wp2 = (const float*)d_in[11];
  const float* bp2 = (const float*)d_in[12];
  const float* W3l = (const float*)d_in[13];
  const float* b3l = (const float*)d_in[14];
  const float* W3r = (const float*)d_in[15];
  const float* Wp3 = (const float*)d_in[16];
  const float* bp3 = (const float*)d_in[17];
  const float* l1w = (const float*)d_in[18];
  const float* l1b = (const float*)d_in[19];
  const float* l2w = (const float*)d_in[20];
  const float* l2b = (const float*)d_in[21];
  const float* l3w = (const float*)d_in[22];
  const float* l3b = (const float*)d_in[23];
  float* out = (float*)d_out;

  char* ws = (char*)d_ws;
  size_t off = 0;
  auto alloc = [&](size_t bytes)->char*{
    char* p = ws + off; off = (off + bytes + 255) & ~(size_t)255; return p;
  };

  // zero group (mx + per-graph edge counters)
  size_t z0 = off;
  u32* mx     = (u32*)alloc(64);
  int* ecnt1g = (int*)alloc(NB*4);
  int* ecnt2g = (int*)alloc(NB*4);
  size_t zend = off;
  // -1 group (inv arrays, init once)
  size_t m0 = off;
  int* inv1 = (int*)alloc((size_t)NN1*4);
  int* inv2 = (int*)alloc((size_t)NN2*4);
  int* inv3 = (int*)alloc((size_t)NN3*4);
  size_t mend = off;
  // rest
  int* rps   = (int*)alloc((size_t)NN1*4);
  int* rpd   = (int*)alloc((size_t)NN1*4);
  int* adj   = (int*)alloc((size_t)EDGESV*4);
  int* eAs   = (int*)alloc((size_t)EDGESV*4);
  int* eAd   = (int*)alloc((size_t)EDGESV*4);
  int* eBs   = (int*)alloc((size_t)EDGESV*4);
  int* eBd   = (int*)alloc((size_t)EDGESV*4);
  u16* B1h   = (u16*)alloc((size_t)KSTEP1*8192*2);
  u16* B1l   = (u16*)alloc((size_t)KSTEP1*8192*2);
  u16* B2h   = (u16*)alloc((size_t)KSTEP2*8192*2);
  u16* B2l   = (u16*)alloc((size_t)KSTEP2*8192*2);
  u16* B3h   = (u16*)alloc((size_t)KSTEP2*8192*2);
  u16* B3l   = (u16*)alloc((size_t)KSTEP2*8192*2);
  float* hcomb = (float*)alloc((size_t)NN1*256*4);
  float* x1    = (float*)alloc((size_t)NN1*128*4);
  float* x2    = (float*)alloc((size_t)NN2*128*4);
  float* x3    = (float*)alloc((size_t)NN3*128*4);
  float* xp1   = (float*)alloc((size_t)NN2*128*4);
  float* xp2   = (float*)alloc((size_t)NN3*128*4);
  float* xp3   = (float*)alloc((size_t)NN4*128*4);
  float* hsc   = (float*)alloc((size_t)NN1*4);
  float* pscale= (float*)alloc((size_t)NN2*4);
  int* perm    = (int*)alloc((size_t)NN2*4);
  float* r1    = (float*)alloc((size_t)32*256*4);
  float* r2    = (float*)alloc((size_t)32*256*4);
  float* r3    = (float*)alloc((size_t)32*256*4);

  int zn = (int)((zend - z0) / 4);
  int mn = (int)((mend - m0) / 4);
  int initn = (zn > mn ? zn : mn);
  init_kernel<<<(initn+255)/256, 256, 0, stream>>>((int*)(ws+z0), zn, (int*)(ws+m0), mn);

  colmax_kernel<<<64, 256, 0, stream>>>(x, mx);
  wprep_all<<<((KSTEP1+2*KSTEP2)*8192+255)/256, 256, 0, stream>>>(
      W1l, W1r, W2l, W2r, W3l, W3r, mx, B1h, B1l, B2h, B2l, B3h, B3l);

  // ===== stage 1 =====
  csr_kernel<<<NB, 1024, 0, stream>>>(esrc, edst, nullptr, 0, N0V, rps, rpd, adj);
  gemm_split_kernel<<<NN1/64, 256, 0, stream>>>(x, FEATV, NN1, FEATV, KSTEP1, B1h, B1l, hcomb);
  convfin_kernel<<<NN1/4, 256, 0, stream>>>(hcomb, rps, rpd, adj, b1l, Wp1, x1, hsc, NN1);
  topk_kernel<<<NB, 256, 0, stream>>>(hsc, rps, rpd, adj, bp1, N0V, KK1, perm, inv1, pscale);
  poolro_kernel<<<NB, 512, 0, stream>>>(x1, perm, pscale, KK1, xp1, r1,
                                        esrc, edst, nullptr, 0, N0V, inv1, KK1,
                                        eAs, eAd, ecnt1g);

  // ===== stage 2 =====
  csr_kernel<<<NB, 1024, 0, stream>>>(eAs, eAd, ecnt1g, 1, KK1, rps, rpd, adj);
  gemm_split_kernel<<<NN2/64, 256, 0, stream>>>(xp1, 128, NN2, 128, KSTEP2, B2h, B2l, hcomb);
  convfin_kernel<<<(NN2+3)/4, 256, 0, stream>>>(hcomb, rps, rpd, adj, b2l, Wp2, x2, hsc, NN2);
  topk_kernel<<<NB, 256, 0, stream>>>(hsc, rps, rpd, adj, bp2, KK1, KK2, perm, inv2, pscale);
  poolro_kernel<<<NB, 512, 0, stream>>>(x2, perm, pscale, KK2, xp2, r2,
                                        eAs, eAd, ecnt1g, 1, KK1, inv2, KK2,
                                        eBs, eBd, ecnt2g);

  // ===== stage 3 =====
  csr_kernel<<<NB, 1024, 0, stream>>>(eBs, eBd, ecnt2g, 1, KK2, rps, rpd, adj);
  gemm_split_kernel<<<NN3/64, 256, 0, stream>>>(xp2, 128, NN3, 128, KSTEP2, B3h, B3l, hcomb);
  convfin_kernel<<<(NN3+3)/4, 256, 0, stream>>>(hcomb, rps, rpd, adj, b3l, Wp3, x3, hsc, NN3);
  topk_kernel<<<NB, 256, 0, stream>>>(hsc, rps, rpd, adj, bp3, KK2, KK3, perm, inv3, pscale);
  poolro_kernel<<<NB, 512, 0, stream>>>(x3, perm, pscale, KK3, xp3, r3,
                                        eBs, eBd, ecnt2g, 1, KK2, inv3, KK3,
                                        nullptr, nullptr, nullptr);

  // ===== head =====
  head_kernel<<<1, 256, 0, stream>>>(r1, r2, r3, l1w, l1b, l2w, l2b, l3w, l3b, out);
}